// Round 1
// baseline (308.557 us; speedup 1.0000x reference)
//
#include <hip/hip_runtime.h>
#include <math.h>

// Problem constants (from reference): L=28, B=3, H=8, S=2048, D=128, V=152064
#define LAY 28
#define BEAM 3
#define NH 8
#define SEQ 2048
#define HD 128
#define VOCAB 152064
#define TOPK 3
#define NBLK 32                 // blocks per logits row in pass_a
#define CHUNK (VOCAB / NBLK)    // 4752 (exact)

static_assert(VOCAB % NBLK == 0, "chunking must be exact");

// Per-(row,block) partial: online-LSE state + stable top-3
struct Partial {
    float m, s;
    float v[3];
    int   idx[3];
};

__device__ __forceinline__ bool better(float a, int ai, float b, int bi) {
    // strict value order; ties broken by LOWER index (jax.lax.top_k semantics)
    return (a > b) || (a == b && ai < bi);
}

__device__ __forceinline__ void ins3(float x, int gi,
                                     float& v0, int& i0,
                                     float& v1, int& i1,
                                     float& v2, int& i2) {
    if (!better(x, gi, v2, i2)) return;
    if (better(x, gi, v0, i0)) { v2 = v1; i2 = i1; v1 = v0; i1 = i0; v0 = x; i0 = gi; }
    else if (better(x, gi, v1, i1)) { v2 = v1; i2 = i1; v1 = x; i1 = gi; }
    else { v2 = x; i2 = gi; }
}

// ---------------- pass A: per-chunk online LSE + top-3 ----------------
__global__ __launch_bounds__(256) void pass_a(const float* __restrict__ logits,
                                              Partial* __restrict__ part) {
    __shared__ float sm[256], ss[256];
    __shared__ float sv[256][3];
    __shared__ int   sidx[256][3];

    const int row  = blockIdx.x / NBLK;
    const int blk  = blockIdx.x % NBLK;
    const int base = blk * CHUNK;
    const float* p = logits + (size_t)row * VOCAB + base;

    float m = -INFINITY, s = 0.f;
    float v0 = -INFINITY, v1 = -INFINITY, v2 = -INFINITY;
    int   i0 = 0x7fffffff, i1 = 0x7fffffff, i2 = 0x7fffffff;

    for (int i = threadIdx.x; i < CHUNK; i += 256) {
        float x = p[i];
        if (x > m) { s = s * expf(m - x) + 1.f; m = x; }
        else       { s += expf(x - m); }
        ins3(x, base + i, v0, i0, v1, i1, v2, i2);
    }

    const int t = threadIdx.x;
    sm[t] = m; ss[t] = s;
    sv[t][0] = v0; sv[t][1] = v1; sv[t][2] = v2;
    sidx[t][0] = i0; sidx[t][1] = i1; sidx[t][2] = i2;
    __syncthreads();

    for (int w = 128; w >= 1; w >>= 1) {
        if (t < w) {
            float mo = sm[t + w], so = ss[t + w];
            float M  = fmaxf(m, mo);
            s = s * expf(m - M) + so * expf(mo - M);
            m = M;
            sm[t] = m; ss[t] = s;
            #pragma unroll
            for (int k = 0; k < 3; ++k)
                ins3(sv[t + w][k], sidx[t + w][k], v0, i0, v1, i1, v2, i2);
            sv[t][0] = v0; sv[t][1] = v1; sv[t][2] = v2;
            sidx[t][0] = i0; sidx[t][1] = i1; sidx[t][2] = i2;
        }
        __syncthreads();
    }

    if (t == 0) {
        Partial q;
        q.m = m; q.s = s;
        q.v[0] = v0; q.v[1] = v1; q.v[2] = v2;
        q.idx[0] = i0; q.idx[1] = i1; q.idx[2] = i2;
        part[blockIdx.x] = q;
    }
}

// ---------------- pass B: merge partials, beam selection, tail outputs ----------------
__global__ void pass_b(const Partial* __restrict__ part,
                       const int* __restrict__ save_id,
                       const float* __restrict__ prev_prob,
                       float* __restrict__ out_tail,   // d_out + OUT_KV
                       int* __restrict__ beam_ws,
                       int hist) {
    __shared__ float lse_s[BEAM];
    __shared__ float v_s[BEAM][3];
    __shared__ int   i_s[BEAM][3];

    const int t = threadIdx.x;
    if (t < BEAM) {
        float m = -INFINITY, s = 0.f;
        float v0 = -INFINITY, v1 = -INFINITY, v2 = -INFINITY;
        int   i0 = 0x7fffffff, i1 = 0x7fffffff, i2 = 0x7fffffff;
        for (int b = 0; b < NBLK; ++b) {
            Partial q = part[t * NBLK + b];
            float M = fmaxf(m, q.m);
            s = s * expf(m - M) + q.s * expf(q.m - M);
            m = M;
            #pragma unroll
            for (int k = 0; k < 3; ++k)
                ins3(q.v[k], q.idx[k], v0, i0, v1, i1, v2, i2);
        }
        lse_s[t] = m + logf(s);
        v_s[t][0] = v0; v_s[t][1] = v1; v_s[t][2] = v2;
        i_s[t][0] = i0; i_s[t][1] = i1; i_s[t][2] = i2;
    }
    __syncthreads();

    if (t == 0) {
        float cp[BEAM * 3];
        for (int r = 0; r < BEAM; ++r)
            for (int k = 0; k < 3; ++k)
                cp[r * 3 + k] = v_s[r][k] - lse_s[r] + prev_prob[r];

        int  sel[3];
        bool used[BEAM * 3] = {false, false, false, false, false, false, false, false, false};
        for (int j = 0; j < 3; ++j) {
            int best = -1;
            for (int c = 0; c < BEAM * 3; ++c) {
                if (used[c]) continue;
                if (best < 0 || cp[c] > cp[best]) best = c;  // scan order => lowest idx wins ties
            }
            used[best] = true;
            sel[j] = best;
        }

        int tok0 = 0;
        for (int j = 0; j < 3; ++j) {
            const int beam = sel[j] / 3;
            const int tok  = i_s[beam][sel[j] % 3];
            if (j == 0) tok0 = tok;
            beam_ws[j] = beam;
            // top_beam_indices [3,1]
            out_tail[j] = (float)tok;
            // new_save_id [3, hist+1]
            for (int h = 0; h < hist; ++h)
                out_tail[3 + j * (hist + 1) + h] = (float)save_id[beam * hist + h];
            out_tail[3 + j * (hist + 1) + hist] = (float)tok;
            // top_beam_prob [3,1]
            out_tail[3 + 3 * (hist + 1) + j] = cp[sel[j]];
        }
        // max_logits_idx [1]
        out_tail[3 + 3 * (hist + 1) + 3] = (float)tok0;
    }
}

// ---------------- pass C: KV gather-copy (the 1.4 GB mover) ----------------
__global__ __launch_bounds__(256) void copy_kv(const float4* __restrict__ src,
                                               const int* __restrict__ beam,
                                               float4* __restrict__ dst) {
    const size_t CH4 = (size_t)NH * SEQ * HD / 4;   // 524288 = 2^19
    const size_t N4  = (size_t)LAY * BEAM * CH4;    // 44,040,192
    static_assert(((size_t)NH * SEQ * HD / 4) == (1u << 19), "chunk must be 2^19 float4s");

    const int b0 = beam[0], b1 = beam[1], b2 = beam[2];
    const size_t stride = (size_t)gridDim.x * blockDim.x;
    for (size_t i = (size_t)blockIdx.x * blockDim.x + threadIdx.x; i < N4; i += stride) {
        const size_t c   = i >> 19;          // chunk id in [0, 84)
        const size_t off = i & (CH4 - 1);
        const int l  = (int)(c / 3);
        const int bp = (int)(c - (size_t)l * 3);
        const int sb = (bp == 0) ? b0 : ((bp == 1) ? b1 : b2);
        dst[i] = src[((size_t)(l * BEAM + sb)) * CH4 + off];
    }
}

extern "C" void kernel_launch(void* const* d_in, const int* in_sizes, int n_in,
                              void* d_out, int out_size, void* d_ws, size_t ws_size,
                              hipStream_t stream) {
    const float* kv        = (const float*)d_in[0];
    const float* logits    = (const float*)d_in[1];
    const int*   save_id   = (const int*)d_in[2];
    const float* prev_prob = (const float*)d_in[3];

    const int hist = in_sizes[2] / BEAM;   // 64
    const size_t OUT_KV = (size_t)LAY * BEAM * NH * SEQ * HD;  // 176,160,768

    float* out     = (float*)d_out;
    int*   beam_ws = (int*)d_ws;
    Partial* part  = (Partial*)((char*)d_ws + 64);

    pass_a<<<BEAM * NBLK, 256, 0, stream>>>(logits, part);
    pass_b<<<1, 64, 0, stream>>>(part, save_id, prev_prob, out + OUT_KV, beam_ws, hist);
    copy_kv<<<4096, 256, 0, stream>>>((const float4*)kv, beam_ws, (float4*)out);
}

// Round 2
// 241.430 us; speedup vs baseline: 1.2780x; 1.2780x over previous
//
#include <hip/hip_runtime.h>
#include <math.h>

// Problem constants (from reference): L=28, B=3, H=8, S=2048, D=128, V=152064
#define LAY 28
#define BEAM 3
#define NH 8
#define SEQ 2048
#define HD 128
#define VOCAB 152064
#define TOPK 3
#define NBLK 32                 // blocks per logits row in pass_a
#define CHUNK (VOCAB / NBLK)    // 4752 (exact), = 1188 float4
#define CHUNK4 (CHUNK / 4)

static_assert(VOCAB % NBLK == 0, "chunking must be exact");
static_assert(CHUNK % 4 == 0, "chunk must be float4-divisible");

typedef float f32x4 __attribute__((ext_vector_type(4)));

// Per-(row,block) partial: online-LSE state + stable top-3
struct Partial {
    float m, s;
    float v[3];
    int   idx[3];
};

__device__ __forceinline__ bool better(float a, int ai, float b, int bi) {
    // strict value order; ties broken by LOWER index (jax.lax.top_k semantics)
    return (a > b) || (a == b && ai < bi);
}

__device__ __forceinline__ void ins3(float x, int gi,
                                     float& v0, int& i0,
                                     float& v1, int& i1,
                                     float& v2, int& i2) {
    if (!better(x, gi, v2, i2)) return;
    if (better(x, gi, v0, i0)) { v2 = v1; i2 = i1; v1 = v0; i1 = i0; v0 = x; i0 = gi; }
    else if (better(x, gi, v1, i1)) { v2 = v1; i2 = i1; v1 = x; i1 = gi; }
    else { v2 = x; i2 = gi; }
}

// ---------------- pass A: per-chunk online LSE + top-3 (float4 loads) ----------------
__global__ __launch_bounds__(256) void pass_a(const float* __restrict__ logits,
                                              Partial* __restrict__ part) {
    __shared__ float sm[256], ss[256];
    __shared__ float sv[256][3];
    __shared__ int   sidx[256][3];

    const int row  = blockIdx.x / NBLK;
    const int blk  = blockIdx.x % NBLK;
    const int base = blk * CHUNK;
    const f32x4* p = (const f32x4*)(logits + (size_t)row * VOCAB + base);

    float m = -INFINITY, s = 0.f;
    float v0 = -INFINITY, v1 = -INFINITY, v2 = -INFINITY;
    int   i0 = 0x7fffffff, i1 = 0x7fffffff, i2 = 0x7fffffff;

    for (int i = threadIdx.x; i < CHUNK4; i += 256) {
        f32x4 x4 = p[i];
        #pragma unroll
        for (int k = 0; k < 4; ++k) {
            float x = x4[k];
            if (x > m) { s = s * expf(m - x) + 1.f; m = x; }
            else       { s += expf(x - m); }
            ins3(x, base + i * 4 + k, v0, i0, v1, i1, v2, i2);
        }
    }

    const int t = threadIdx.x;
    sm[t] = m; ss[t] = s;
    sv[t][0] = v0; sv[t][1] = v1; sv[t][2] = v2;
    sidx[t][0] = i0; sidx[t][1] = i1; sidx[t][2] = i2;
    __syncthreads();

    for (int w = 128; w >= 1; w >>= 1) {
        if (t < w) {
            float mo = sm[t + w], so = ss[t + w];
            float M  = fmaxf(m, mo);
            s = s * expf(m - M) + so * expf(mo - M);
            m = M;
            sm[t] = m; ss[t] = s;
            #pragma unroll
            for (int k = 0; k < 3; ++k)
                ins3(sv[t + w][k], sidx[t + w][k], v0, i0, v1, i1, v2, i2);
            sv[t][0] = v0; sv[t][1] = v1; sv[t][2] = v2;
            sidx[t][0] = i0; sidx[t][1] = i1; sidx[t][2] = i2;
        }
        __syncthreads();
    }

    if (t == 0) {
        Partial q;
        q.m = m; q.s = s;
        q.v[0] = v0; q.v[1] = v1; q.v[2] = v2;
        q.idx[0] = i0; q.idx[1] = i1; q.idx[2] = i2;
        part[blockIdx.x] = q;
    }
}

// ---------------- pass B: merge partials, beam selection, tail outputs ----------------
__global__ void pass_b(const Partial* __restrict__ part,
                       const int* __restrict__ save_id,
                       const float* __restrict__ prev_prob,
                       float* __restrict__ out_tail,   // d_out + OUT_KV
                       int* __restrict__ beam_ws,
                       int hist) {
    __shared__ float lse_s[BEAM];
    __shared__ float v_s[BEAM][3];
    __shared__ int   i_s[BEAM][3];

    const int t = threadIdx.x;
    if (t < BEAM) {
        float m = -INFINITY, s = 0.f;
        float v0 = -INFINITY, v1 = -INFINITY, v2 = -INFINITY;
        int   i0 = 0x7fffffff, i1 = 0x7fffffff, i2 = 0x7fffffff;
        for (int b = 0; b < NBLK; ++b) {
            Partial q = part[t * NBLK + b];
            float M = fmaxf(m, q.m);
            s = s * expf(m - M) + q.s * expf(q.m - M);
            m = M;
            #pragma unroll
            for (int k = 0; k < 3; ++k)
                ins3(q.v[k], q.idx[k], v0, i0, v1, i1, v2, i2);
        }
        lse_s[t] = m + logf(s);
        v_s[t][0] = v0; v_s[t][1] = v1; v_s[t][2] = v2;
        i_s[t][0] = i0; i_s[t][1] = i1; i_s[t][2] = i2;
    }
    __syncthreads();

    if (t == 0) {
        float cp[BEAM * 3];
        for (int r = 0; r < BEAM; ++r)
            for (int k = 0; k < 3; ++k)
                cp[r * 3 + k] = v_s[r][k] - lse_s[r] + prev_prob[r];

        int  sel[3];
        bool used[BEAM * 3] = {false, false, false, false, false, false, false, false, false};
        for (int j = 0; j < 3; ++j) {
            int best = -1;
            for (int c = 0; c < BEAM * 3; ++c) {
                if (used[c]) continue;
                if (best < 0 || cp[c] > cp[best]) best = c;  // scan order => lowest idx wins ties
            }
            used[best] = true;
            sel[j] = best;
        }

        int tok0 = 0;
        for (int j = 0; j < 3; ++j) {
            const int beam = sel[j] / 3;
            const int tok  = i_s[beam][sel[j] % 3];
            if (j == 0) tok0 = tok;
            beam_ws[j] = beam;
            // top_beam_indices [3,1]
            out_tail[j] = (float)tok;
            // new_save_id [3, hist+1]
            for (int h = 0; h < hist; ++h)
                out_tail[3 + j * (hist + 1) + h] = (float)save_id[beam * hist + h];
            out_tail[3 + j * (hist + 1) + hist] = (float)tok;
            // top_beam_prob [3,1]
            out_tail[3 + 3 * (hist + 1) + j] = cp[sel[j]];
        }
        // max_logits_idx [1]
        out_tail[3 + 3 * (hist + 1) + 3] = (float)tok0;
    }
}

// ---------------- pass C: KV gather-copy (the 1.4 GB mover) ----------------
// 4096 blocks x 256 threads = 2^20 threads; N4 = 42 * 2^20 exactly -> no bounds check.
__global__ __launch_bounds__(256) void copy_kv(const f32x4* __restrict__ src,
                                               const int* __restrict__ beam,
                                               f32x4* __restrict__ dst) {
    constexpr size_t CH4 = (size_t)NH * SEQ * HD / 4;   // 524288 = 2^19
    constexpr size_t N4  = (size_t)LAY * BEAM * CH4;    // 44,040,192 = 42 * 2^20
    static_assert(CH4 == ((size_t)1 << 19), "chunk must be 2^19 float4s");
    static_assert(N4 % ((size_t)4096 * 256) == 0, "grid must divide N4 exactly");

    // Pre-resolved source base pointer per output chunk (l, beam-slot)
    __shared__ const f32x4* sbase[LAY * BEAM];
    if (threadIdx.x < LAY * BEAM) {
        const int c  = threadIdx.x;
        const int l  = c / 3;
        const int bp = c - l * 3;
        sbase[c] = src + ((size_t)(l * 3 + beam[bp])) * CH4;
    }
    __syncthreads();

    const size_t stride = (size_t)4096 * 256;
    size_t i = (size_t)blockIdx.x * 256 + threadIdx.x;
    #pragma unroll 2
    for (int it = 0; it < 42; ++it, i += stride) {
        const f32x4* sp = sbase[i >> 19];
        f32x4 v = sp[i & (CH4 - 1)];
        __builtin_nontemporal_store(v, &dst[i]);   // dst is never re-read: bypass cache
    }
}

extern "C" void kernel_launch(void* const* d_in, const int* in_sizes, int n_in,
                              void* d_out, int out_size, void* d_ws, size_t ws_size,
                              hipStream_t stream) {
    const float* kv        = (const float*)d_in[0];
    const float* logits    = (const float*)d_in[1];
    const int*   save_id   = (const int*)d_in[2];
    const float* prev_prob = (const float*)d_in[3];

    const int hist = in_sizes[2] / BEAM;   // 64
    const size_t OUT_KV = (size_t)LAY * BEAM * NH * SEQ * HD;  // 176,160,768

    float* out     = (float*)d_out;
    int*   beam_ws = (int*)d_ws;
    Partial* part  = (Partial*)((char*)d_ws + 64);

    pass_a<<<BEAM * NBLK, 256, 0, stream>>>(logits, part);
    pass_b<<<1, 64, 0, stream>>>(part, save_id, prev_prob, out + OUT_KV, beam_ws, hist);
    copy_kv<<<4096, 256, 0, stream>>>((const f32x4*)kv, beam_ws, (f32x4*)out);
}